// Round 4
// baseline (31.840 us; speedup 1.0000x reference)
//
#include <hip/hip_runtime.h>
#include <hip/hip_bf16.h>

// B=4, S=512, H=128
// out[b,i,h] = tanh( (1/L_b) * sum_j m_i*m_j * inp[b,j,h] * sigmoid(g0[b,i,h]+g1[b,j,h]) )
// t = e0*e1;  x*sigmoid = x - x*re1/(re1 + e0),  re1 = exp(-g1)
// -> per (i,j,h): shared {sumx += x, xr = x*re1}; per chain: add + rcp + fma.

#define BB 4
#define SS 512
#define HH 128
#define RA 8           // rows per kA block
#define L2E 1.44269504088896f

// ---------------- prep: W transpose + mask compaction ----------------
// grid: 33 blocks x 256. Blocks 0..31: WT[g][k][o] = W_g[o][k]. Block 32: compaction.
__global__ __launch_bounds__(256) void k_prep(const float* __restrict__ W0,
                                              const float* __restrict__ W1,
                                              const int* __restrict__ masks,
                                              float* __restrict__ WT,
                                              int* __restrict__ valid_idx,
                                              int* __restrict__ nvalid,
                                              float* __restrict__ rcpL) {
    if (blockIdx.x == 32) {
        int wave = threadIdx.x >> 6, lane = threadIdx.x & 63;
        if (wave >= BB) return;
        int b = wave, base = 0;
        for (int c = 0; c < SS; c += 64) {
            int m = masks[b * SS + c + lane];
            unsigned long long bits = __ballot(m != 0);
            int pos = __popcll(bits & ((1ull << lane) - 1ull));
            if (m) valid_idx[b * SS + base + pos] = c + lane;
            base += __popcll(bits);
        }
        if (lane == 0) {
            nvalid[b] = base;
            rcpL[b] = base ? 1.0f / (float)base : 0.0f;
        }
        return;
    }
    // 32 blocks x 256 threads = 8192 = 2 gates * 128 o * 32 k4
    const int flat = blockIdx.x * 256 + threadIdx.x;
    const int g = flat >> 12;
    const int rem = flat & 4095;
    const int k4 = rem >> 7;    // 0..31
    const int o = rem & 127;    // consecutive lanes -> consecutive o (coalesced stores)
    const float* __restrict__ W = g ? W1 : W0;
    float4 w = *(const float4*)(W + (size_t)o * HH + k4 * 4);
    float* __restrict__ WTg = WT + (size_t)g * HH * HH;
    WTg[(size_t)(k4 * 4 + 0) * HH + o] = w.x;
    WTg[(size_t)(k4 * 4 + 1) * HH + o] = w.y;
    WTg[(size_t)(k4 * 4 + 2) * HH + o] = w.z;
    WTg[(size_t)(k4 * 4 + 3) * HH + o] = w.w;
}

// ---------------- kA: gates GEMM + exp + pack ----------------
// grid: BB*SS/RA = 256 blocks, 256 threads (o = tid&127, g = tid>>7).
// W coalesced via WT[k][o]; x rows are wave-uniform (scalar loads).
__global__ __launch_bounds__(256) void kA(const float* __restrict__ inp,
                                          const int* __restrict__ masks,
                                          const float* __restrict__ WT,
                                          const float* __restrict__ b0,
                                          const float* __restrict__ b1,
                                          float* __restrict__ E0,
                                          float2* __restrict__ XE,
                                          float* __restrict__ out) {
    const int row0 = blockIdx.x * RA;
    const int o = threadIdx.x & 127;
    const int g = threadIdx.x >> 7;
    const float bias = g ? b1[o] : b0[o];
    const float* __restrict__ WTg = WT + (size_t)g * HH * HH;
    const float* __restrict__ xbase = inp + (size_t)row0 * HH;

    float acc[RA];
#pragma unroll
    for (int r = 0; r < RA; ++r) acc[r] = bias;

#pragma unroll 8
    for (int k = 0; k < HH; ++k) {
        const float w = WTg[(size_t)k * HH + o];   // coalesced dword
#pragma unroll
        for (int r = 0; r < RA; ++r)
            acc[r] = fmaf(xbase[(size_t)r * HH + k], w, acc[r]);  // uniform -> SGPR
    }

    if (g == 0) {
#pragma unroll
        for (int r = 0; r < RA; ++r)
            E0[(size_t)(row0 + r) * HH + o] = __builtin_amdgcn_exp2f(acc[r] * L2E);
#pragma unroll
        for (int r = 0; r < RA; ++r)
            if (masks[row0 + r] == 0) out[(size_t)(row0 + r) * HH + o] = 0.0f;
    } else {
#pragma unroll
        for (int r = 0; r < RA; ++r) {
            const float re1 = __builtin_amdgcn_exp2f(-acc[r] * L2E);  // exp(-g1)
            const float x = inp[(size_t)(row0 + r) * HH + o];
            XE[(size_t)(row0 + r) * HH + o] = make_float2(x, re1);
        }
    }
}

// ---------------- kB: pairwise + in-block reduce + tanh ----------------
// grid: B * (SS/4) = 512 blocks, 1024 threads (8 j-octants x 128 h).
__global__ __launch_bounds__(1024) void kB(const float* __restrict__ E0,
                                           const float2* __restrict__ XE,
                                           const int* __restrict__ valid_idx,
                                           const int* __restrict__ nvalid,
                                           const float* __restrict__ rcpL,
                                           float* __restrict__ out) {
    const int b = blockIdx.x >> 7;
    const int qi = blockIdx.x & 127;
    const int nv = nvalid[b];
    const int p0 = qi * 4;
    if (p0 >= nv) return;

    __shared__ float red[8][4][HH];    // 16 KB
    __shared__ int s_vj[SS];           // 2 KB

    const int tid = threadIdx.x;
    const int h = tid & 127;
    const int oc = tid >> 7;

    if (tid < nv) s_vj[tid] = valid_idx[b * SS + tid];
    __syncthreads();

    const size_t boff = (size_t)b * SS * HH;
    const float* __restrict__ E0b = E0 + boff;
    const float2* __restrict__ XEb = XE + boff;

    float e0r[4];
#pragma unroll
    for (int r = 0; r < 4; ++r)
        e0r[r] = (p0 + r < nv) ? E0b[(size_t)s_vj[p0 + r] * HH + h] : 0.0f;

    const int chunk = (nv + 7) >> 3;
    const int jb = oc * chunk;
    const int je = min(nv, jb + chunk);

    // x*sigma = x - xr * rcp(re1 + e0),  xr = x*re1  (shared across 4 chains)
    float acc[4] = {0.f, 0.f, 0.f, 0.f};
    float sumx = 0.f;
#pragma unroll 4
    for (int t = jb; t < je; ++t) {
        const int j = s_vj[t];
        const float2 v = XEb[(size_t)j * HH + h];  // {x, re1}
        const float x = v.x, re1 = v.y;
        sumx += x;
        const float xr = x * re1;
#pragma unroll
        for (int r = 0; r < 4; ++r)
            acc[r] = fmaf(xr, __builtin_amdgcn_rcpf(re1 + e0r[r]), acc[r]);
    }

#pragma unroll
    for (int r = 0; r < 4; ++r) red[oc][r][h] = sumx - acc[r];
    __syncthreads();

    if (tid < 512) {
        const int r = tid >> 7;
        if (p0 + r < nv) {
            const int hh = tid & 127;
            float s = 0.f;
#pragma unroll
            for (int q = 0; q < 8; ++q) s += red[q][r][hh];
            float x = s * rcpL[b];
            x = fminf(fmaxf(x, -30.0f), 30.0f);
            const float e = __builtin_amdgcn_exp2f(x * 2.885390081777927f); // exp(2x)
            const float th = (e - 1.0f) * __builtin_amdgcn_rcpf(e + 1.0f);
            out[boff + (size_t)s_vj[p0 + r] * HH + hh] = th;
        }
    }
}

extern "C" void kernel_launch(void* const* d_in, const int* in_sizes, int n_in,
                              void* d_out, int out_size, void* d_ws, size_t ws_size,
                              hipStream_t stream) {
    const float* inp = (const float*)d_in[0];
    const int* masks = (const int*)d_in[1];
    const float* W0 = (const float*)d_in[2];
    const float* b0 = (const float*)d_in[3];
    const float* W1 = (const float*)d_in[4];
    const float* b1 = (const float*)d_in[5];
    float* out = (float*)d_out;

    const size_t nBSH = (size_t)BB * SS * HH;  // 262144
    float* E0 = (float*)d_ws;                  // 1 MB
    float2* XE = (float2*)(E0 + nBSH);         // 2 MB
    float* WT = (float*)(XE + nBSH);           // 128 KB
    int* valid_idx = (int*)(WT + 2 * HH * HH); // 8 KB
    int* nvalid = valid_idx + BB * SS;
    float* rcpL = (float*)(nvalid + BB);

    k_prep<<<33, 256, 0, stream>>>(W0, W1, masks, WT, valid_idx, nvalid, rcpL);
    kA<<<(BB * SS) / RA, 256, 0, stream>>>(inp, masks, WT, b0, b1, E0, XE, out);
    kB<<<BB * (SS / 4), 1024, 0, stream>>>(E0, XE, valid_idx, nvalid, rcpL, out);
}

// Round 5
// 30.635 us; speedup vs baseline: 1.0393x; 1.0393x over previous
//
#include <hip/hip_runtime.h>
#include <hip/hip_bf16.h>

// B=4, S=512, H=128
// out[b,i,h] = tanh( (1/L_b) * sum_j m_i*m_j * inp[b,j,h] * sigmoid(g0[b,i,h]+g1[b,j,h]) )
// t = e0*e1; x*sigmoid = x - x*re1/(re1 + e0), re1 = exp(-g1)
// kA: per-block LDS-staged W (XOR-swizzled float4 tiles), VALU GEMV + exp + pack.
// kB: compacted-j pairwise loop, 8-way j-split in-block, LDS reduce + tanh.

#define BB 4
#define SS 512
#define HH 128
#define RA 8
#define L2E 1.44269504088896f

// ---------------- kernel A: gates + exp + pack + compaction ----------------
// grid: 513 blocks x 256. Block bid<512: g = bid&1, rows [ (bid>>1)*RA, +RA ).
// Block 512: mask compaction.
// LDS: sW[q*128 + (o^q)] = W_g[o][4q..4q+3]  (q=k>>2 in [0,32), o in [0,128))
//   stage-write lanes vary q  -> conflict-free ds_write_b128
//   compute-read lanes vary o -> conflict-free ds_read_b128
__global__ __launch_bounds__(256) void kA(const float* __restrict__ inp,
                                          const int* __restrict__ masks,
                                          const float* __restrict__ W0,
                                          const float* __restrict__ b0,
                                          const float* __restrict__ W1,
                                          const float* __restrict__ b1,
                                          float* __restrict__ E0,
                                          float2* __restrict__ XE,
                                          int* __restrict__ valid_idx,
                                          int* __restrict__ nvalid,
                                          float* __restrict__ rcpL,
                                          float* __restrict__ out) {
    const int bid = blockIdx.x;
    if (bid == 512) {
        int wave = threadIdx.x >> 6, lane = threadIdx.x & 63;
        if (wave >= BB) return;
        int b = wave, base = 0;
        for (int c = 0; c < SS; c += 64) {
            int m = masks[b * SS + c + lane];
            unsigned long long bits = __ballot(m != 0);
            int pos = __popcll(bits & ((1ull << lane) - 1ull));
            if (m) valid_idx[b * SS + base + pos] = c + lane;
            base += __popcll(bits);
        }
        if (lane == 0) {
            nvalid[b] = base;
            rcpL[b] = base ? 1.0f / (float)base : 0.0f;
        }
        return;
    }

    __shared__ float4 sW[32 * 128];   // 64 KB

    const int g = bid & 1;
    const int row0 = (bid >> 1) * RA;
    const float* __restrict__ W = g ? W1 : W0;

    // stage W: 4096 float4, 256 threads x 16 iters, fully coalesced reads
#pragma unroll
    for (int it = 0; it < 16; ++it) {
        const int flat = it * 256 + threadIdx.x;   // 0..4095
        const int q = flat & 31;                   // k>>2
        const int o = flat >> 5;                   // 0..127
        const float4 w = *(const float4*)(W + (size_t)o * HH + q * 4);
        sW[q * 128 + (o ^ q)] = w;
    }
    __syncthreads();

    const int o = threadIdx.x & 127;
    const int rh = threadIdx.x >> 7;               // wave-uniform
    const int r0 = row0 + rh * 4;
    const float* __restrict__ xb = inp + (size_t)r0 * HH;
    const float bias = g ? b1[o] : b0[o];

    float acc[4] = {bias, bias, bias, bias};
#pragma unroll 4
    for (int q = 0; q < 32; ++q) {
        const float4 w = sW[q * 128 + (o ^ q)];    // W[o][4q..4q+3]
#pragma unroll
        for (int r = 0; r < 4; ++r) {
            const float4 x = *(const float4*)(xb + (size_t)r * HH + q * 4); // wave-uniform
            float a = acc[r];
            a = fmaf(x.x, w.x, a);
            a = fmaf(x.y, w.y, a);
            a = fmaf(x.z, w.z, a);
            a = fmaf(x.w, w.w, a);
            acc[r] = a;
        }
    }

    if (g == 0) {
#pragma unroll
        for (int r = 0; r < 4; ++r)
            E0[(size_t)(r0 + r) * HH + o] = __builtin_amdgcn_exp2f(acc[r] * L2E);
#pragma unroll
        for (int r = 0; r < 4; ++r)
            if (masks[r0 + r] == 0) out[(size_t)(r0 + r) * HH + o] = 0.0f;
    } else {
#pragma unroll
        for (int r = 0; r < 4; ++r) {
            const float re1 = __builtin_amdgcn_exp2f(-acc[r] * L2E); // exp(-g1)
            const float x = inp[(size_t)(r0 + r) * HH + o];
            XE[(size_t)(r0 + r) * HH + o] = make_float2(x, re1);
        }
    }
}

// ---------------- kernel B: pairwise + in-block reduce + tanh ----------------
// grid: B * (SS/4) = 512 blocks, 1024 threads (8 j-octants x 128 h).
__global__ __launch_bounds__(1024) void kB(const float* __restrict__ E0,
                                           const float2* __restrict__ XE,
                                           const int* __restrict__ valid_idx,
                                           const int* __restrict__ nvalid,
                                           const float* __restrict__ rcpL,
                                           float* __restrict__ out) {
    const int b = blockIdx.x >> 7;
    const int qi = blockIdx.x & 127;
    const int nv = nvalid[b];
    const int p0 = qi * 4;
    if (p0 >= nv) return;

    __shared__ float red[8][4][HH];    // 16 KB
    __shared__ int s_vj[SS];           // 2 KB

    const int tid = threadIdx.x;
    const int h = tid & 127;
    const int oc = tid >> 7;

    if (tid < nv) s_vj[tid] = valid_idx[b * SS + tid];
    __syncthreads();

    const size_t boff = (size_t)b * SS * HH;
    const float* __restrict__ E0b = E0 + boff;
    const float2* __restrict__ XEb = XE + boff;

    float e0r[4];
#pragma unroll
    for (int r = 0; r < 4; ++r)
        e0r[r] = (p0 + r < nv) ? E0b[(size_t)s_vj[p0 + r] * HH + h] : 0.0f;

    const int chunk = (nv + 7) >> 3;
    const int jb = oc * chunk;
    const int je = min(nv, jb + chunk);

    // x*sigma = x - xr * rcp(re1 + e0), xr = x*re1 (shared across 4 chains)
    float acc[4] = {0.f, 0.f, 0.f, 0.f};
    float sumx = 0.f;
#pragma unroll 8
    for (int t = jb; t < je; ++t) {
        const int j = s_vj[t];
        const float2 v = XEb[(size_t)j * HH + h];  // {x, re1}
        const float x = v.x, re1 = v.y;
        sumx += x;
        const float xr = x * re1;
#pragma unroll
        for (int r = 0; r < 4; ++r)
            acc[r] = fmaf(xr, __builtin_amdgcn_rcpf(re1 + e0r[r]), acc[r]);
    }

#pragma unroll
    for (int r = 0; r < 4; ++r) red[oc][r][h] = sumx - acc[r];
    __syncthreads();

    if (tid < 512) {
        const int r = tid >> 7;
        if (p0 + r < nv) {
            const int hh = tid & 127;
            float s = 0.f;
#pragma unroll
            for (int q = 0; q < 8; ++q) s += red[q][r][hh];
            float x = s * rcpL[b];
            x = fminf(fmaxf(x, -30.0f), 30.0f);
            const float e = __builtin_amdgcn_exp2f(x * 2.885390081777927f); // exp(2x)
            const float th = (e - 1.0f) * __builtin_amdgcn_rcpf(e + 1.0f);
            out[boff + (size_t)s_vj[p0 + r] * HH + hh] = th;
        }
    }
}

extern "C" void kernel_launch(void* const* d_in, const int* in_sizes, int n_in,
                              void* d_out, int out_size, void* d_ws, size_t ws_size,
                              hipStream_t stream) {
    const float* inp = (const float*)d_in[0];
    const int* masks = (const int*)d_in[1];
    const float* W0 = (const float*)d_in[2];
    const float* b0 = (const float*)d_in[3];
    const float* W1 = (const float*)d_in[4];
    const float* b1 = (const float*)d_in[5];
    float* out = (float*)d_out;

    const size_t nBSH = (size_t)BB * SS * HH;  // 262144
    float* E0 = (float*)d_ws;                  // 1 MB
    float2* XE = (float2*)(E0 + nBSH);         // 2 MB
    int* valid_idx = (int*)(XE + nBSH);        // 8 KB
    int* nvalid = valid_idx + BB * SS;
    float* rcpL = (float*)(nvalid + BB);

    kA<<<513, 256, 0, stream>>>(inp, masks, W0, b0, W1, b1,
                                E0, XE, valid_idx, nvalid, rcpL, out);
    kB<<<BB * (SS / 4), 1024, 0, stream>>>(E0, XE, valid_idx, nvalid, rcpL, out);
}